// Round 1
// baseline (9.611 us; speedup 1.0000x reference)
//
#include <hip/hip_runtime.h>

// HBV hydrological step: one thread per basin (B = 100000).
// Inputs (setup_inputs order): y (B,5) f32, theta (B,13) f32,
// climate_data (T,B,3) f32, t (1,) int32.
// Output: dS (B,5) f32 flattened, then fluxes (B,1) f32 — total 6B floats.

__global__ __launch_bounds__(256) void hbv_step_kernel(
    const float* __restrict__ y,
    const float* __restrict__ theta,
    const float* __restrict__ clim,
    const int* __restrict__ tptr,
    float* __restrict__ out,
    int B)
{
    const int b = blockIdx.x * blockDim.x + threadIdx.x;
    if (b >= B) return;

    const int t = tptr[0];

    const float* yr = y + (size_t)b * 5;
    const float* th = theta + (size_t)b * 13;
    const float* cr = clim + ((size_t)t * (size_t)B + (size_t)b) * 3;

    // Parameter unscaling: lo + theta*(hi-lo)
    const float parBETA   = 1.0f   + th[0]  * (6.0f   - 1.0f);
    const float parFC     = 50.0f  + th[1]  * (1000.0f- 50.0f);
    const float parK0     = 0.05f  + th[2]  * (0.9f   - 0.05f);
    const float parK1     = 0.01f  + th[3]  * (0.5f   - 0.01f);
    const float parK2     = 0.001f + th[4]  * (0.2f   - 0.001f);
    const float parLP     = 0.2f   + th[5]  * (1.0f   - 0.2f);
    const float parPERC   = 0.0f   + th[6]  * (10.0f  - 0.0f);
    const float parUZL    = 0.0f   + th[7]  * (100.0f - 0.0f);
    const float parTT     = -2.5f  + th[8]  * (2.5f   - (-2.5f));
    const float parCFMAX  = 0.5f   + th[9]  * (10.0f  - 0.5f);
    const float parCFR    = 0.0f   + th[10] * (0.1f   - 0.0f);
    const float parCWH    = 0.0f   + th[11] * (0.2f   - 0.0f);
    const float parBETAET = 0.3f   + th[12] * (5.0f   - 0.3f);

    // State clipping
    const float SNOWPACK  = fmaxf(yr[0], 0.0f);
    const float MELTWATER = fmaxf(yr[1], 0.0f);
    const float SM        = fmaxf(yr[2], 1e-8f);
    const float SUZ       = fmaxf(yr[3], 0.0f);
    const float SLZ       = fmaxf(yr[4], 0.0f);

    const float P  = cr[0];
    const float T_ = cr[1];
    const float Ep = cr[2];

    // Fluxes
    const float flux_sf    = (T_ < parTT) ? P : 0.0f;
    const float flux_refr  = fminf(fmaxf(parCFR * parCFMAX * (parTT - T_), 0.0f), MELTWATER);
    const float flux_melt  = fminf(fmaxf(parCFMAX * (T_ - parTT), 0.0f), SNOWPACK);
    const float flux_rf    = (T_ >= parTT) ? P : 0.0f;
    const float flux_Isnow = fmaxf(MELTWATER - parCWH * SNOWPACK, 0.0f);

    const float soil_wetness = fminf(fmaxf(powf(SM / parFC, parBETA), 0.0f), 1.0f);
    const float flux_PEFF  = (flux_rf + flux_Isnow) * soil_wetness;
    const float flux_ex    = fmaxf(SM - parFC, 0.0f);
    const float evapfactor = fminf(fmaxf(powf(SM / (parLP * parFC), parBETAET), 0.0f), 1.0f);
    const float flux_et    = fminf(SM, Ep * evapfactor);

    const float flux_perc  = fminf(SUZ, parPERC);
    const float flux_q0    = parK0 * fmaxf(SUZ - parUZL, 0.0f);
    const float flux_q1    = parK1 * SUZ;
    const float flux_q2    = parK2 * SLZ;

    // Outputs: dS (B,5) row-major, then fluxes (B,)
    float* dS = out + (size_t)b * 5;
    dS[0] = flux_sf + flux_refr - flux_melt;
    dS[1] = flux_melt - flux_refr - flux_Isnow;
    dS[2] = flux_Isnow + flux_rf - flux_PEFF - flux_ex - flux_et;
    dS[3] = flux_PEFF + flux_ex - flux_perc - flux_q0 - flux_q1;
    dS[4] = flux_perc - flux_q2;
    out[(size_t)B * 5 + b] = flux_q0 + flux_q1 + flux_q2;
}

extern "C" void kernel_launch(void* const* d_in, const int* in_sizes, int n_in,
                              void* d_out, int out_size, void* d_ws, size_t ws_size,
                              hipStream_t stream) {
    const float* y     = (const float*)d_in[0];
    const float* theta = (const float*)d_in[1];
    const float* clim  = (const float*)d_in[2];
    const int*   tptr  = (const int*)d_in[3];
    float* out = (float*)d_out;

    const int B = in_sizes[0] / 5;  // y is (B,5)

    const int block = 256;
    const int grid = (B + block - 1) / block;
    hbv_step_kernel<<<grid, block, 0, stream>>>(y, theta, clim, tptr, out, B);
}